// Round 9
// baseline (546.169 us; speedup 1.0000x reference)
//
#include <hip/hip_runtime.h>
#include <hip/hip_bf16.h>

#define NV 100000
#define NE 25000
#define NNZ_ 1600000
#define CH 256
#define ESTRIDE 128   // max edge degree (Poisson λ=64, +8σ)
#define VSTRIDE 48    // max vertex degree (Poisson λ=16, +8σ)
#define LDSK 264      // 256 + 8 u16 pad -> 528B row stride, 2-way-max LDS bank aliasing

typedef unsigned int u32;
typedef unsigned short u16;
typedef __attribute__((ext_vector_type(8))) short bf16x8;
typedef __attribute__((ext_vector_type(4))) float f32x4;

__device__ __forceinline__ float bf2f(u16 u){ return __uint_as_float(((u32)u)<<16); }
__device__ __forceinline__ u16 f2bf(float f){ __hip_bfloat16 h = __float2bfloat16(f); return *reinterpret_cast<u16*>(&h); }
__device__ __forceinline__ void acc4(float4& a, ushort4 u){
  a.x += bf2f(u.x); a.y += bf2f(u.y); a.z += bf2f(u.z); a.w += bf2f(u.w);
}

// ---- 1. fused padded-CSR build (r7 structure, u16 v-list) ----
__global__ void k_build(const int* __restrict__ v_idx, const int* __restrict__ e_idx,
                        int* __restrict__ dv_cnt, int* __restrict__ de_cnt,
                        u16* __restrict__ v_listP, int* __restrict__ e_listP){
  int part = blockIdx.x & 7;
  int grp  = blockIdx.x >> 3;
  int ngrp = gridDim.x >> 3;
  int eLo = part*(NE/8), eHi = eLo + (NE/8);
  int vLo = part*(NV/8), vHi = vLo + (NV/8);
  int i = grp*blockDim.x + threadIdx.x;
  int stride = ngrp*blockDim.x;
  for (; i<NNZ_; i+=stride){
    int v = __builtin_nontemporal_load(&v_idx[i]);
    int e = __builtin_nontemporal_load(&e_idx[i]);
    if (e>=eLo && e<eHi){ int s = atomicAdd(&de_cnt[e],1); e_listP[(e<<7)+s] = v; }
    if (v>=vLo && v<vHi){ int s = atomicAdd(&dv_cnt[v],1); v_listP[v*VSTRIDE+s] = (u16)e; }
  }
}

// ---- 2. dv^-1/2 ----
__global__ void k_dvis(const int* __restrict__ dv_cnt, float* __restrict__ dv_isqrt){
  int v = blockIdx.x*blockDim.x + threadIdx.x;
  if (v < NV){ int d = dv_cnt[v]; dv_isqrt[v] = d>0 ? rsqrtf((float)d) : 0.f; }
}

// ---- 3. Xs = dv_isqrt * X, cast to bf16 ----
__global__ void k_xs(const float4* __restrict__ X4, const float* __restrict__ dv_isqrt,
                     ushort4* __restrict__ Xs4){
  int i = blockIdx.x*blockDim.x + threadIdx.x;
  int v = i >> 6;
  float w = dv_isqrt[v];
  float4 x = X4[i];
  ushort4 o;
  o.x = f2bf(x.x*w); o.y = f2bf(x.y*w); o.z = f2bf(x.z*w); o.w = f2bf(x.w*w);
  Xs4[i] = o;
}

// ---- 4. Wh[n][k] = bf16(W[k][n])  (transpose for MFMA B-operand) ----
__global__ void k_wh(const float* __restrict__ W, u16* __restrict__ Wh){
  __shared__ float tile[16][17];
  int bx=blockIdx.x, by=blockIdx.y;
  int tx=threadIdx.x, ty=threadIdx.y;
  tile[ty][tx] = W[(by*16+ty)*256 + bx*16+tx];
  __syncthreads();
  Wh[(bx*16+ty)*256 + by*16+tx] = f2bf(tile[tx][ty]);
}

// ---- 5. fused: gather Te-tile (16 edges) -> LDS bf16 -> MFMA @ Wh -> Ue bf16
//      also computes tb[e] inline. Kills Te buffer, k_tb, and the VALU GEMM. ----
__global__ __launch_bounds__(256) void k_tegemm(const int* __restrict__ de_cnt,
                     const int* __restrict__ e_listP, const ushort4* __restrict__ Xs4,
                     const float* __restrict__ dv_isqrt, const u16* __restrict__ Wh,
                     float* __restrict__ tb, u16* __restrict__ Ue){
  __shared__ u16 lds[16][LDSK];
  int t = threadIdx.x, w = t>>6, lane = t&63;
  int e0 = blockIdx.x*16;

  // Phase 1: each wave gathers 4 edge rows; lane covers 4 channels
  for (int j=0;j<4;++j){
    int e = e0 + w*4 + j;
    int r = w*4 + j;
    float4 a0=make_float4(0,0,0,0), a1=make_float4(0,0,0,0);
    float ts = 0.f;
    if (e < NE){
      int deg = de_cnt[e], base = e<<7;
      int m = 0;
      for (; m+8 <= deg; m += 8){
        int v0=e_listP[base+m+0], v1=e_listP[base+m+1], v2=e_listP[base+m+2], v3=e_listP[base+m+3];
        int v4=e_listP[base+m+4], v5=e_listP[base+m+5], v6=e_listP[base+m+6], v7=e_listP[base+m+7];
        ushort4 u0=Xs4[(v0<<6)+lane], u1=Xs4[(v1<<6)+lane], u2=Xs4[(v2<<6)+lane], u3=Xs4[(v3<<6)+lane];
        ushort4 u4=Xs4[(v4<<6)+lane], u5=Xs4[(v5<<6)+lane], u6=Xs4[(v6<<6)+lane], u7=Xs4[(v7<<6)+lane];
        acc4(a0,u0); acc4(a1,u1); acc4(a0,u2); acc4(a1,u3);
        acc4(a0,u4); acc4(a1,u5); acc4(a0,u6); acc4(a1,u7);
        ts += dv_isqrt[v0]+dv_isqrt[v1]+dv_isqrt[v2]+dv_isqrt[v3]
            + dv_isqrt[v4]+dv_isqrt[v5]+dv_isqrt[v6]+dv_isqrt[v7];
      }
      for (; m<deg; ++m){
        int v = e_listP[base+m];
        ushort4 u = Xs4[(v<<6)+lane];
        acc4(a0,u);
        ts += dv_isqrt[v];
      }
      float dinv = deg>0 ? 1.f/(float)deg : 0.f;
      a0.x=(a0.x+a1.x)*dinv; a0.y=(a0.y+a1.y)*dinv; a0.z=(a0.z+a1.z)*dinv; a0.w=(a0.w+a1.w)*dinv;
      if (lane==0) tb[e] = ts*dinv;
    }
    ushort4 o;
    o.x=f2bf(a0.x); o.y=f2bf(a0.y); o.z=f2bf(a0.z); o.w=f2bf(a0.w);
    *reinterpret_cast<ushort4*>(&lds[r][lane*4]) = o;   // zeros when e>=NE
  }
  __syncthreads();

  // Phase 2: 16x256 = A(16x256 in LDS) @ Wh^T ; wave w covers col-tiles w*4..w*4+3
  int rr = lane & 15, kg = lane >> 4;
  f32x4 acc0={0,0,0,0}, acc1={0,0,0,0}, acc2={0,0,0,0}, acc3={0,0,0,0};
  #pragma unroll
  for (int s=0; s<8; ++s){
    bf16x8 a = *reinterpret_cast<bf16x8*>(&lds[rr][s*32 + kg*8]);
    const u16* wb = &Wh[(size_t)((w*4)*16 + rr)*256 + s*32 + kg*8];
    bf16x8 b0 = *reinterpret_cast<const bf16x8*>(wb);
    bf16x8 b1 = *reinterpret_cast<const bf16x8*>(wb + 16*256);
    bf16x8 b2 = *reinterpret_cast<const bf16x8*>(wb + 32*256);
    bf16x8 b3 = *reinterpret_cast<const bf16x8*>(wb + 48*256);
    acc0 = __builtin_amdgcn_mfma_f32_16x16x32_bf16(a, b0, acc0, 0,0,0);
    acc1 = __builtin_amdgcn_mfma_f32_16x16x32_bf16(a, b1, acc1, 0,0,0);
    acc2 = __builtin_amdgcn_mfma_f32_16x16x32_bf16(a, b2, acc2, 0,0,0);
    acc3 = __builtin_amdgcn_mfma_f32_16x16x32_bf16(a, b3, acc3, 0,0,0);
  }
  __syncthreads();
  // D layout: col = lane&15, row = (lane>>4)*4 + reg  (m89/m91-verified)
  #pragma unroll
  for (int reg=0; reg<4; ++reg){
    int row = kg*4 + reg;
    lds[row][(w*4+0)*16 + rr] = f2bf(acc0[reg]);
    lds[row][(w*4+1)*16 + rr] = f2bf(acc1[reg]);
    lds[row][(w*4+2)*16 + rr] = f2bf(acc2[reg]);
    lds[row][(w*4+3)*16 + rr] = f2bf(acc3[reg]);
  }
  __syncthreads();
  // coalesced store: thread t -> edge row t>>4, 32B segment t&15
  int orow = t>>4, oseg = t&15;
  int e = e0 + orow;
  if (e < NE){
    uint4 d0 = *reinterpret_cast<uint4*>(&lds[orow][oseg*16]);
    uint4 d1 = *reinterpret_cast<uint4*>(&lds[orow][oseg*16+8]);
    *reinterpret_cast<uint4*>(&Ue[(size_t)e*256 + oseg*16])     = d0;
    *reinterpret_cast<uint4*>(&Ue[(size_t)e*256 + oseg*16 + 8]) = d1;
  }
}

// ---- 6. out[v] = relu( dv_isqrt[v]*(sum Ue[e]) + dv_isqrt[v]*(sum tb[e])*b )
//      channel-chunked: 4 grid phases, each gathers a 3.2MB Ue chunk (L2-resident) ----
__global__ __launch_bounds__(256) void k_zv(const int* __restrict__ dv_cnt, const u16* __restrict__ v_listP,
                    const ushort4* __restrict__ Ue4, const float* __restrict__ tb,
                    const float* __restrict__ dv_isqrt, const float4* __restrict__ b4,
                    float4* __restrict__ out4){
  const int nvb = NV/16;                 // 6250
  int chunk = blockIdx.x / nvb;          // 0..3 (dispatch-order phased)
  int vb    = blockIdx.x % nvb;
  int g  = threadIdx.x >> 4;             // vertex group 0..15
  int lc = threadIdx.x & 15;             // lane-in-group: 4 channels
  int v = vb*16 + g;
  int deg = dv_cnt[v];
  int base = v*VSTRIDE;
  float w = dv_isqrt[v];
  float sb = 0.f;
  for (int m=0; m<deg; ++m) sb += tb[v_listP[base+m]];   // broadcast loads
  float sw = sb*w;
  int coff = chunk*16 + lc;
  float4 a0 = make_float4(0,0,0,0), a1 = make_float4(0,0,0,0);
  int m = 0;
  for (; m+4 <= deg; m += 4){
    int e0=v_listP[base+m+0], e1=v_listP[base+m+1], e2=v_listP[base+m+2], e3=v_listP[base+m+3];
    ushort4 u0=Ue4[(e0<<6)+coff], u1=Ue4[(e1<<6)+coff], u2=Ue4[(e2<<6)+coff], u3=Ue4[(e3<<6)+coff];
    acc4(a0,u0); acc4(a1,u1); acc4(a0,u2); acc4(a1,u3);
  }
  for (; m<deg; ++m){
    int e = v_listP[base+m];
    acc4(a0, Ue4[(e<<6)+coff]);
  }
  float4 bb = b4[coff];
  float4 o;
  o.x = fmaxf(0.f, fmaf(sw, bb.x, (a0.x+a1.x)*w));
  o.y = fmaxf(0.f, fmaf(sw, bb.y, (a0.y+a1.y)*w));
  o.z = fmaxf(0.f, fmaf(sw, bb.z, (a0.z+a1.z)*w));
  o.w = fmaxf(0.f, fmaf(sw, bb.w, (a0.w+a1.w)*w));
  out4[(v<<6)+coff] = o;
}

extern "C" void kernel_launch(void* const* d_in, const int* in_sizes, int n_in,
                              void* d_out, int out_size, void* d_ws, size_t ws_size,
                              hipStream_t stream) {
  const float* X = (const float*)d_in[0];
  const float* W = (const float*)d_in[1];
  const float* b = (const float*)d_in[2];
  const int* v_idx = (const int*)d_in[3];
  const int* e_idx = (const int*)d_in[4];
  float* out = (float*)d_out;

  char* p = (char*)d_ws;
  auto alloc = [&](size_t bytes)->void*{
    void* r = (void*)p; p += (bytes + 255) & ~(size_t)255; return r;
  };
  int* dv_cnt     = (int*)alloc((size_t)NV*4);
  int* de_cnt     = (int*)alloc((size_t)NE*4);
  float* dv_isqrt = (float*)alloc((size_t)NV*4);
  float* tb       = (float*)alloc((size_t)NE*4);
  int* e_listP    = (int*)alloc((size_t)NE*ESTRIDE*4);   // 12.8 MB
  u16* v_listP    = (u16*)alloc((size_t)NV*VSTRIDE*2);   // 9.6 MB
  u16* Wh         = (u16*)alloc((size_t)CH*CH*2);        // 128 KB
  u16* Ue         = (u16*)alloc((size_t)NE*CH*2);        // 12.8 MB
  u16* Xs         = (u16*)d_out;      // staging inside d_out (dead before k_zv writes)

  hipMemsetAsync(dv_cnt, 0, (size_t)NV*4, stream);
  hipMemsetAsync(de_cnt, 0, (size_t)NE*4, stream);

  k_build<<<1024,256,0,stream>>>(v_idx,e_idx,dv_cnt,de_cnt,v_listP,e_listP);
  k_dvis<<<(NV+255)/256,256,0,stream>>>(dv_cnt, dv_isqrt);
  k_xs<<<(NV*64)/256,256,0,stream>>>((const float4*)X, dv_isqrt, (ushort4*)Xs);
  k_wh<<<dim3(16,16),dim3(16,16),0,stream>>>(W, Wh);
  k_tegemm<<<(NE+15)/16,256,0,stream>>>(de_cnt,e_listP,(const ushort4*)Xs,dv_isqrt,Wh,tb,Ue);
  k_zv<<<(NV/16)*4,256,0,stream>>>(dv_cnt,v_listP,(const ushort4*)Ue,tb,dv_isqrt,(const float4*)b,(float4*)out);
}

// Round 10
// 437.139 us; speedup vs baseline: 1.2494x; 1.2494x over previous
//
#include <hip/hip_runtime.h>
#include <hip/hip_bf16.h>

#define NV 100000
#define NE 25000
#define NNZ_ 1600000
#define CH 256
#define ESTRIDE 128   // max edge degree (Poisson λ=64, +8σ)
#define VSTRIDE 48    // max vertex degree (Poisson λ=16, +8σ)
#define LDSK 264      // 256 + 8 u16 pad -> 528B row stride

typedef unsigned int u32;
typedef unsigned short u16;
typedef __attribute__((ext_vector_type(8))) short bf16x8;
typedef __attribute__((ext_vector_type(4))) float f32x4;

__device__ __forceinline__ float bf2f(u16 u){ return __uint_as_float(((u32)u)<<16); }
__device__ __forceinline__ u16 f2bf(float f){ __hip_bfloat16 h = __float2bfloat16(f); return *reinterpret_cast<u16*>(&h); }
__device__ __forceinline__ void acc4(float4& a, ushort4 u){
  a.x += bf2f(u.x); a.y += bf2f(u.y); a.z += bf2f(u.z); a.w += bf2f(u.w);
}

// ---- 1. fused padded-CSR build ----
__global__ void k_build(const int* __restrict__ v_idx, const int* __restrict__ e_idx,
                        int* __restrict__ dv_cnt, int* __restrict__ de_cnt,
                        u16* __restrict__ v_listP, int* __restrict__ e_listP){
  int part = blockIdx.x & 7;
  int grp  = blockIdx.x >> 3;
  int ngrp = gridDim.x >> 3;
  int eLo = part*(NE/8), eHi = eLo + (NE/8);
  int vLo = part*(NV/8), vHi = vLo + (NV/8);
  int i = grp*blockDim.x + threadIdx.x;
  int stride = ngrp*blockDim.x;
  for (; i<NNZ_; i+=stride){
    int v = __builtin_nontemporal_load(&v_idx[i]);
    int e = __builtin_nontemporal_load(&e_idx[i]);
    if (e>=eLo && e<eHi){ int s = atomicAdd(&de_cnt[e],1); e_listP[(e<<7)+s] = v; }
    if (v>=vLo && v<vHi){ int s = atomicAdd(&dv_cnt[v],1); v_listP[v*VSTRIDE+s] = (u16)e; }
  }
}

// ---- 2. dv^-1/2 ----
__global__ void k_dvis(const int* __restrict__ dv_cnt, float* __restrict__ dv_isqrt){
  int v = blockIdx.x*blockDim.x + threadIdx.x;
  if (v < NV){ int d = dv_cnt[v]; dv_isqrt[v] = d>0 ? rsqrtf((float)d) : 0.f; }
}

// ---- 3. Xs = dv_isqrt * X, cast to bf16 ----
__global__ void k_xs(const float4* __restrict__ X4, const float* __restrict__ dv_isqrt,
                     ushort4* __restrict__ Xs4){
  int i = blockIdx.x*blockDim.x + threadIdx.x;
  int v = i >> 6;
  float w = dv_isqrt[v];
  float4 x = X4[i];
  ushort4 o;
  o.x = f2bf(x.x*w); o.y = f2bf(x.y*w); o.z = f2bf(x.z*w); o.w = f2bf(x.w*w);
  Xs4[i] = o;
}

// ---- 4. Wh[n][k] = bf16(W[k][n]) ----
__global__ void k_wh(const float* __restrict__ W, u16* __restrict__ Wh){
  __shared__ float tile[16][17];
  int bx=blockIdx.x, by=blockIdx.y;
  int tx=threadIdx.x, ty=threadIdx.y;
  tile[ty][tx] = W[(by*16+ty)*256 + bx*16+tx];
  __syncthreads();
  Wh[(bx*16+ty)*256 + by*16+tx] = f2bf(tile[tx][ty]);
}

// ---- 5. fused: gather 16-edge tile -> LDS bf16 -> MFMA @ Wh -> Ue bf16 (+tb) ----
__global__ __launch_bounds__(256) void k_tegemm(const int* __restrict__ de_cnt,
                     const int* __restrict__ e_listP, const ushort4* __restrict__ Xs4,
                     const float* __restrict__ dv_isqrt, const u16* __restrict__ Wh,
                     float* __restrict__ tb, u16* __restrict__ Ue){
  __shared__ u16 lds[16][LDSK];
  int t = threadIdx.x, w = t>>6, lane = t&63;
  int e0 = blockIdx.x*16;

  for (int j=0;j<4;++j){
    int e = e0 + w*4 + j;
    int r = w*4 + j;
    float4 a0=make_float4(0,0,0,0), a1=make_float4(0,0,0,0);
    float ts = 0.f;
    if (e < NE){
      int deg = de_cnt[e], base = e<<7;
      int m = 0;
      for (; m+8 <= deg; m += 8){
        int v0=e_listP[base+m+0], v1=e_listP[base+m+1], v2=e_listP[base+m+2], v3=e_listP[base+m+3];
        int v4=e_listP[base+m+4], v5=e_listP[base+m+5], v6=e_listP[base+m+6], v7=e_listP[base+m+7];
        ushort4 u0=Xs4[(v0<<6)+lane], u1=Xs4[(v1<<6)+lane], u2=Xs4[(v2<<6)+lane], u3=Xs4[(v3<<6)+lane];
        ushort4 u4=Xs4[(v4<<6)+lane], u5=Xs4[(v5<<6)+lane], u6=Xs4[(v6<<6)+lane], u7=Xs4[(v7<<6)+lane];
        acc4(a0,u0); acc4(a1,u1); acc4(a0,u2); acc4(a1,u3);
        acc4(a0,u4); acc4(a1,u5); acc4(a0,u6); acc4(a1,u7);
        ts += dv_isqrt[v0]+dv_isqrt[v1]+dv_isqrt[v2]+dv_isqrt[v3]
            + dv_isqrt[v4]+dv_isqrt[v5]+dv_isqrt[v6]+dv_isqrt[v7];
      }
      for (; m<deg; ++m){
        int v = e_listP[base+m];
        ushort4 u = Xs4[(v<<6)+lane];
        acc4(a0,u);
        ts += dv_isqrt[v];
      }
      float dinv = deg>0 ? 1.f/(float)deg : 0.f;
      a0.x=(a0.x+a1.x)*dinv; a0.y=(a0.y+a1.y)*dinv; a0.z=(a0.z+a1.z)*dinv; a0.w=(a0.w+a1.w)*dinv;
      if (lane==0) tb[e] = ts*dinv;
    }
    ushort4 o;
    o.x=f2bf(a0.x); o.y=f2bf(a0.y); o.z=f2bf(a0.z); o.w=f2bf(a0.w);
    *reinterpret_cast<ushort4*>(&lds[r][lane*4]) = o;
  }
  __syncthreads();

  int rr = lane & 15, kg = lane >> 4;
  f32x4 acc0={0,0,0,0}, acc1={0,0,0,0}, acc2={0,0,0,0}, acc3={0,0,0,0};
  #pragma unroll
  for (int s=0; s<8; ++s){
    bf16x8 a = *reinterpret_cast<bf16x8*>(&lds[rr][s*32 + kg*8]);
    const u16* wb = &Wh[(size_t)((w*4)*16 + rr)*256 + s*32 + kg*8];
    bf16x8 b0 = *reinterpret_cast<const bf16x8*>(wb);
    bf16x8 b1 = *reinterpret_cast<const bf16x8*>(wb + 16*256);
    bf16x8 b2 = *reinterpret_cast<const bf16x8*>(wb + 32*256);
    bf16x8 b3 = *reinterpret_cast<const bf16x8*>(wb + 48*256);
    acc0 = __builtin_amdgcn_mfma_f32_16x16x32_bf16(a, b0, acc0, 0,0,0);
    acc1 = __builtin_amdgcn_mfma_f32_16x16x32_bf16(a, b1, acc1, 0,0,0);
    acc2 = __builtin_amdgcn_mfma_f32_16x16x32_bf16(a, b2, acc2, 0,0,0);
    acc3 = __builtin_amdgcn_mfma_f32_16x16x32_bf16(a, b3, acc3, 0,0,0);
  }
  __syncthreads();
  #pragma unroll
  for (int reg=0; reg<4; ++reg){
    int row = kg*4 + reg;
    lds[row][(w*4+0)*16 + rr] = f2bf(acc0[reg]);
    lds[row][(w*4+1)*16 + rr] = f2bf(acc1[reg]);
    lds[row][(w*4+2)*16 + rr] = f2bf(acc2[reg]);
    lds[row][(w*4+3)*16 + rr] = f2bf(acc3[reg]);
  }
  __syncthreads();
  int orow = t>>4, oseg = t&15;
  int e = e0 + orow;
  if (e < NE){
    uint4 d0 = *reinterpret_cast<uint4*>(&lds[orow][oseg*16]);
    uint4 d1 = *reinterpret_cast<uint4*>(&lds[orow][oseg*16+8]);
    *reinterpret_cast<uint4*>(&Ue[(size_t)e*256 + oseg*16])     = d0;
    *reinterpret_cast<uint4*>(&Ue[(size_t)e*256 + oseg*16 + 8]) = d1;
  }
}

// ---- 6. out[v] = relu( dv_isqrt[v]*(sum Ue[e]) + dv_isqrt[v]*(sum tb[e])*b )
//      wave-per-vertex, 8-deep MLP unroll (r8 known-good form) ----
__global__ __launch_bounds__(256) void k_zv(const int* __restrict__ dv_cnt, const u16* __restrict__ v_listP,
                    const ushort4* __restrict__ Ue4, const float* __restrict__ tb,
                    const float* __restrict__ dv_isqrt, const float4* __restrict__ b4,
                    float4* __restrict__ out4){
  int v = blockIdx.x*4 + (threadIdx.x>>6);
  if (v >= NV) return;
  int lane = threadIdx.x & 63;
  int deg = dv_cnt[v];
  int base = v*VSTRIDE;
  float4 a0 = make_float4(0,0,0,0), a1 = make_float4(0,0,0,0);
  float sb0 = 0.f, sb1 = 0.f;
  int m = 0;
  for (; m+8 <= deg; m += 8){
    int e0=v_listP[base+m+0], e1=v_listP[base+m+1], e2=v_listP[base+m+2], e3=v_listP[base+m+3];
    int e4=v_listP[base+m+4], e5=v_listP[base+m+5], e6=v_listP[base+m+6], e7=v_listP[base+m+7];
    ushort4 u0=Ue4[(e0<<6)+lane], u1=Ue4[(e1<<6)+lane], u2=Ue4[(e2<<6)+lane], u3=Ue4[(e3<<6)+lane];
    ushort4 u4=Ue4[(e4<<6)+lane], u5=Ue4[(e5<<6)+lane], u6=Ue4[(e6<<6)+lane], u7=Ue4[(e7<<6)+lane];
    acc4(a0,u0); acc4(a1,u1); acc4(a0,u2); acc4(a1,u3);
    acc4(a0,u4); acc4(a1,u5); acc4(a0,u6); acc4(a1,u7);
    sb0 += tb[e0]+tb[e2]+tb[e4]+tb[e6];
    sb1 += tb[e1]+tb[e3]+tb[e5]+tb[e7];
  }
  for (; m<deg; ++m){
    int e = v_listP[base+m];
    ushort4 u = Ue4[(e<<6)+lane];
    acc4(a0,u);
    sb0 += tb[e];
  }
  float4 acc;
  acc.x=a0.x+a1.x; acc.y=a0.y+a1.y; acc.z=a0.z+a1.z; acc.w=a0.w+a1.w;
  float w = dv_isqrt[v];
  float sw = (sb0+sb1)*w;
  float4 bb = b4[lane];
  float4 o;
  o.x = fmaxf(0.f, fmaf(sw, bb.x, acc.x*w));
  o.y = fmaxf(0.f, fmaf(sw, bb.y, acc.y*w));
  o.z = fmaxf(0.f, fmaf(sw, bb.z, acc.z*w));
  o.w = fmaxf(0.f, fmaf(sw, bb.w, acc.w*w));
  out4[(v<<6)+lane] = o;
}

extern "C" void kernel_launch(void* const* d_in, const int* in_sizes, int n_in,
                              void* d_out, int out_size, void* d_ws, size_t ws_size,
                              hipStream_t stream) {
  const float* X = (const float*)d_in[0];
  const float* W = (const float*)d_in[1];
  const float* b = (const float*)d_in[2];
  const int* v_idx = (const int*)d_in[3];
  const int* e_idx = (const int*)d_in[4];
  float* out = (float*)d_out;

  char* p = (char*)d_ws;
  auto alloc = [&](size_t bytes)->void*{
    void* r = (void*)p; p += (bytes + 255) & ~(size_t)255; return r;
  };
  int* dv_cnt     = (int*)alloc((size_t)NV*4);
  int* de_cnt     = (int*)alloc((size_t)NE*4);
  float* dv_isqrt = (float*)alloc((size_t)NV*4);
  float* tb       = (float*)alloc((size_t)NE*4);
  int* e_listP    = (int*)alloc((size_t)NE*ESTRIDE*4);   // 12.8 MB
  u16* v_listP    = (u16*)alloc((size_t)NV*VSTRIDE*2);   // 9.6 MB
  u16* Wh         = (u16*)alloc((size_t)CH*CH*2);        // 128 KB
  u16* Ue         = (u16*)alloc((size_t)NE*CH*2);        // 12.8 MB
  u16* Xs         = (u16*)d_out;      // staging inside d_out (dead before k_zv writes)

  hipMemsetAsync(dv_cnt, 0, (size_t)NV*4, stream);
  hipMemsetAsync(de_cnt, 0, (size_t)NE*4, stream);

  k_build<<<1024,256,0,stream>>>(v_idx,e_idx,dv_cnt,de_cnt,v_listP,e_listP);
  k_dvis<<<(NV+255)/256,256,0,stream>>>(dv_cnt, dv_isqrt);
  k_xs<<<(NV*64)/256,256,0,stream>>>((const float4*)X, dv_isqrt, (ushort4*)Xs);
  k_wh<<<dim3(16,16),dim3(16,16),0,stream>>>(W, Wh);
  k_tegemm<<<(NE+15)/16,256,0,stream>>>(de_cnt,e_listP,(const ushort4*)Xs,dv_isqrt,Wh,tb,Ue);
  k_zv<<<(NV+3)/4,256,0,stream>>>(dv_cnt,v_listP,(const ushort4*)Ue,tb,dv_isqrt,(const float4*)b,(float4*)out);
}